// Round 2
// baseline (9143.575 us; speedup 1.0000x reference)
//
#include <hip/hip_runtime.h>

#define VV 100000
#define BB 2048
#define TT 200
#define GG 192   // 3*C
#define PP 514
#define RPB 8    // batch rows per block (mimn_rnn)

__device__ __forceinline__ float sigmf(float x) { return 1.0f / (1.0f + expf(-x)); }
__device__ __forceinline__ float softplusf(float x) {
    return fmaxf(x, 0.0f) + log1pf(expf(-fabsf(x)));
}
__device__ __forceinline__ float wred64(float x) {
#pragma unroll
    for (int m = 32; m >= 1; m >>= 1) x += __shfl_xor(x, m, 64);
    return x;
}

// ---------------- K0: per-vocab GI tables (bih folded into GI_item) -------------
// GIi[v][n] = emb[v]·Wih[n][0:64] + bih[n];  GIc[v][n] = emb[v]·Wih[n][64:128]
__global__ __launch_bounds__(192) void build_tables(
    const float* __restrict__ emb,   // V x 64
    const float* __restrict__ Wih,   // 192 x 256
    const float* __restrict__ bih,   // 192
    float* __restrict__ GIi, float* __restrict__ GIc)  // V x 192 each
{
    __shared__ float sE[64 * 64];    // 16 KB: 64 vocab rows x 64
    int tid = threadIdx.x;           // = n
    int v0 = blockIdx.x * 64;
    for (int i = tid; i < 64 * 64; i += 192) {
        int vv = i >> 6, k = i & 63;
        int gv = v0 + vv;
        sE[i] = (gv < VV) ? emb[(size_t)gv * 64 + k] : 0.0f;
    }
    __syncthreads();
    int n = tid;
    float bi = bih[n];
    // item half
    {
        float4 w[16];
        const float4* wp = (const float4*)(Wih + n * 256);
#pragma unroll
        for (int q = 0; q < 16; ++q) w[q] = wp[q];
        for (int vv = 0; vv < 64; ++vv) {
            int gv = v0 + vv;
            if (gv >= VV) break;
            const float4* e = (const float4*)&sE[vv * 64];
            float acc = bi;
#pragma unroll
            for (int q = 0; q < 16; ++q) {
                float4 ee = e[q];
                acc += w[q].x * ee.x + w[q].y * ee.y + w[q].z * ee.z + w[q].w * ee.w;
            }
            GIi[(size_t)gv * GG + n] = acc;
        }
    }
    // cate half
    {
        float4 w[16];
        const float4* wp = (const float4*)(Wih + n * 256 + 64);
#pragma unroll
        for (int q = 0; q < 16; ++q) w[q] = wp[q];
        for (int vv = 0; vv < 64; ++vv) {
            int gv = v0 + vv;
            if (gv >= VV) break;
            const float4* e = (const float4*)&sE[vv * 64];
            float acc = 0.0f;
#pragma unroll
            for (int q = 0; q < 16; ++q) {
                float4 ee = e[q];
                acc += w[q].x * ee.x + w[q].y * ee.y + w[q].z * ee.z + w[q].w * ee.w;
            }
            GIc[(size_t)gv * GG + n] = acc;
        }
    }
}

// ---------------- K1: hist_sum + seq_len ----------------------------------------
__global__ __launch_bounds__(128) void hist_stats(
    const int* __restrict__ hist_item, const int* __restrict__ hist_cate,
    const float* __restrict__ mask, const float* __restrict__ emb,
    float* __restrict__ hist_sum, int* __restrict__ seqlen)
{
    int b = blockIdx.x, tid = threadIdx.x;
    const int* hidx = (tid < 64) ? hist_item : hist_cate;   // wave-uniform
    int j = tid & 63;
    float acc = 0.f;
    for (int t = 0; t < TT; ++t) {
        float m = mask[b * TT + t];
        int idx = hidx[b * TT + t];
        acc += m * emb[(size_t)idx * 64 + j];
    }
    hist_sum[(size_t)b * 128 + tid] = acc;
    if (tid < 64) {
        float s = 0.f;
        for (int t = tid; t < TT; t += 64) s += mask[b * TT + t];
        s = wred64(s);
        if (tid == 0) seqlen[b] = (int)(s + 0.5f);
    }
}

// ---------------- K2: the recurrence (8 batch rows / block, 512 thr) ------------
__global__ __launch_bounds__(512) void mimn_rnn(
    const int* __restrict__ hist_item, const int* __restrict__ hist_cate,
    const float* __restrict__ mask,
    const float* __restrict__ Wih,   // 192x256 (cols 128..255 = read part)
    const float* __restrict__ Whh,   // 192x64
    const float* __restrict__ bhh,   // 192
    const float* __restrict__ Wp,    // 514x64
    const float* __restrict__ bp,    // 514
    const float* __restrict__ Wo,    // 64x192
    const float* __restrict__ bo,    // 64
    const float* __restrict__ M0,    // 4x128
    const float* __restrict__ GIi, const float* __restrict__ GIc,
    const int* __restrict__ seqlen,
    float* __restrict__ last_out)    // B x 64
{
    __shared__ float sH [RPB * 64];    // committed h
    __shared__ float sHn[RPB * 64];    // unmasked h_new
    __shared__ float sRd[RPB * 128];   // committed read
    __shared__ float sM [RPB * 512];   // memory, 4 slots x 128
    __shared__ float sU [3 * RPB * GG];// ph1-2: partials [part][row][n]; ph3-4: p [row*516+n]

    int tid = threadIdx.x;
    int b0 = blockIdx.x * RPB;
    int wv = tid >> 6, lane = tid & 63;

    for (int i = tid; i < RPB * 64; i += 512) { sH[i] = 0.f; sHn[i] = 0.f; }
    for (int i = tid; i < RPB * 128; i += 512) sRd[i] = 0.f;
    for (int i = tid; i < RPB * 512; i += 512) sM[i] = M0[i & 511];
    int ts = seqlen[b0 + wv] - 1;                     // wave wv owns row wv in ph4
    ts = ts < 0 ? 0 : (ts > TT - 1 ? TT - 1 : ts);
    __syncthreads();

    for (int t = 0; t < TT; ++t) {
        // ---- phase 1: gi (gather + read-part, split k-halves) and gh ----
        if (tid < 384) {                               // waves 0..5
            int n  = (tid < 192) ? tid : tid - 192;
            int k0 = (tid < 192) ? 0 : 64;
            float acc[RPB];
#pragma unroll
            for (int r = 0; r < RPB; ++r) acc[r] = 0.f;
            if (tid < 192) {                           // add gathers once
#pragma unroll
                for (int r = 0; r < RPB; ++r) {
                    int b = b0 + r;
                    int ii = hist_item[b * TT + t], ci = hist_cate[b * TT + t];
                    acc[r] = GIi[(size_t)ii * GG + n] + GIc[(size_t)ci * GG + n];
                }
            }
            const float4* w = (const float4*)(Wih + n * 256 + 128 + k0);
#pragma unroll
            for (int q = 0; q < 16; ++q) {
                float4 wq = w[q];
#pragma unroll
                for (int r = 0; r < RPB; ++r) {
                    const float4 rd = *(const float4*)&sRd[r * 128 + k0 + q * 4];
                    acc[r] += wq.x * rd.x + wq.y * rd.y + wq.z * rd.z + wq.w * rd.w;
                }
            }
            float* dst = &sU[(tid < 192 ? 0 : 1) * (RPB * GG)];
#pragma unroll
            for (int r = 0; r < RPB; ++r) dst[r * GG + n] = acc[r];
        } else {                                       // waves 6..7: gh
            int u = tid - 384;
            for (int n = u; n < GG; n += 128) {
                float acc[RPB];
                float bb = bhh[n];
#pragma unroll
                for (int r = 0; r < RPB; ++r) acc[r] = bb;
                const float4* w = (const float4*)(Whh + n * 64);
#pragma unroll
                for (int q = 0; q < 16; ++q) {
                    float4 wq = w[q];
#pragma unroll
                    for (int r = 0; r < RPB; ++r) {
                        const float4 h4 = *(const float4*)&sH[r * 64 + q * 4];
                        acc[r] += wq.x * h4.x + wq.y * h4.y + wq.z * h4.z + wq.w * h4.w;
                    }
                }
#pragma unroll
                for (int r = 0; r < RPB; ++r) sU[2 * (RPB * GG) + r * GG + n] = acc[r];
            }
        }
        __syncthreads();
        // ---- phase 2: GRU gates; commit h (8 rows x 64 lanes = 512 thr) ----
        {
            const float* P0 = &sU[wv * GG];
            const float* P1 = &sU[RPB * GG + wv * GG];
            const float* P2 = &sU[2 * RPB * GG + wv * GG];
            float rg = sigmf(P0[lane] + P1[lane] + P2[lane]);
            float zg = sigmf(P0[64 + lane] + P1[64 + lane] + P2[64 + lane]);
            float ng = tanhf(P0[128 + lane] + P1[128 + lane] + rg * P2[128 + lane]);
            float h_old = sH[wv * 64 + lane];
            float hn = (1.f - zg) * ng + zg * h_old;
            float mt = mask[(b0 + wv) * TT + t];
            __syncthreads();                            // partials consumed
            sHn[wv * 64 + lane] = hn;
            sH[wv * 64 + lane] = (mt > 0.f) ? hn : h_old;
        }
        __syncthreads();
        // ---- phase 3: p = h_new @ Wp^T + bp  (thread-per-Wp-row) ----
        for (int n = tid; n < PP; n += 512) {
            const float4* wp = (const float4*)(Wp + n * 64);
            float acc[RPB];
            float bb = bp[n];
#pragma unroll
            for (int r = 0; r < RPB; ++r) acc[r] = bb;
#pragma unroll
            for (int q = 0; q < 16; ++q) {
                float4 wq = wp[q];
#pragma unroll
                for (int r = 0; r < RPB; ++r) {
                    const float4 h4 = *(const float4*)&sHn[r * 64 + q * 4];
                    acc[r] += wq.x * h4.x + wq.y * h4.y + wq.z * h4.z + wq.w * h4.w;
                }
            }
#pragma unroll
            for (int r = 0; r < RPB; ++r) sU[r * 516 + n] = acc[r];
        }
        __syncthreads();
        // ---- phase 4: NTM addressing, one wave per batch row ----
        {
            int row = wv;
            int bw = b0 + row;
            float* A = &sU[row * 516];
            float kr1 = tanhf(A[lane]),       kr2 = tanhf(A[64 + lane]);
            float beta_r = softplusf(A[128]);
            float kw1 = tanhf(A[129 + lane]), kw2 = tanhf(A[193 + lane]);
            float beta_w = softplusf(A[257]);
            float er1 = sigmf(A[258 + lane]), er2 = sigmf(A[322 + lane]);
            float ad1 = tanhf(A[386 + lane]), ad2 = tanhf(A[450 + lane]);
            float M1[4], M2[4];
#pragma unroll
            for (int s = 0; s < 4; ++s) {
                M1[s] = sM[row * 512 + s * 128 + lane];
                M2[s] = sM[row * 512 + s * 128 + 64 + lane];
            }
            float nkr = sqrtf(wred64(kr1 * kr1 + kr2 * kr2)) + 1e-8f;
            float nkw = sqrtf(wred64(kw1 * kw1 + kw2 * kw2)) + 1e-8f;
            float Kr[4], Kw[4];
#pragma unroll
            for (int s = 0; s < 4; ++s) {
                float nM = sqrtf(wred64(M1[s] * M1[s] + M2[s] * M2[s])) + 1e-8f;
                float dr = wred64(kr1 * M1[s] + kr2 * M2[s]);
                float dw = wred64(kw1 * M1[s] + kw2 * M2[s]);
                Kr[s] = dr / (nkr * nM);
                Kw[s] = dw / (nkw * nM);
            }
            float wr_[4], ww_[4];
            {
                float mx = fmaxf(fmaxf(beta_r * Kr[0], beta_r * Kr[1]),
                                 fmaxf(beta_r * Kr[2], beta_r * Kr[3]));
                float sum = 0.f;
#pragma unroll
                for (int s = 0; s < 4; ++s) { wr_[s] = expf(beta_r * Kr[s] - mx); sum += wr_[s]; }
                float inv = 1.f / sum;
#pragma unroll
                for (int s = 0; s < 4; ++s) wr_[s] *= inv;
            }
            {
                float mx = fmaxf(fmaxf(beta_w * Kw[0], beta_w * Kw[1]),
                                 fmaxf(beta_w * Kw[2], beta_w * Kw[3]));
                float sum = 0.f;
#pragma unroll
                for (int s = 0; s < 4; ++s) { ww_[s] = expf(beta_w * Kw[s] - mx); sum += ww_[s]; }
                float inv = 1.f / sum;
#pragma unroll
                for (int s = 0; s < 4; ++s) ww_[s] *= inv;
            }
            float rn1 = 0.f, rn2 = 0.f;
#pragma unroll
            for (int s = 0; s < 4; ++s) { rn1 += wr_[s] * M1[s]; rn2 += wr_[s] * M2[s]; }
            float mt = mask[bw * TT + t];
            bool vld = mt > 0.f;
            if (vld) {
#pragma unroll
                for (int s = 0; s < 4; ++s) {
                    sM[row * 512 + s * 128 + lane]      = M1[s] * (1.f - ww_[s] * er1) + ww_[s] * ad1;
                    sM[row * 512 + s * 128 + 64 + lane] = M2[s] * (1.f - ww_[s] * er2) + ww_[s] * ad2;
                }
                sRd[row * 128 + lane]      = rn1;
                sRd[row * 128 + 64 + lane] = rn2;
            }
            if (t == ts) {
                // out = [h_new, read_new] @ Wo^T + bo  (unmasked values)
                A[lane] = rn1; A[64 + lane] = rn2;       // reuse p[0..128) slot
                __asm__ volatile("s_waitcnt lgkmcnt(0)" ::: "memory");
                float acc = bo[lane];
                const float* wo = Wo + lane * GG;
                for (int k = 0; k < 64; ++k)  acc += sHn[row * 64 + k] * wo[k];
                for (int k = 0; k < 128; ++k) acc += A[k] * wo[64 + k];
                if (!vld) acc = 0.f;
                last_out[(size_t)bw * 64 + lane] = acc;
            }
        }
        __syncthreads();
    }
}

// ---------------- K3: final MLP head --------------------------------------------
__global__ __launch_bounds__(128) void final_mlp(
    const int* __restrict__ item, const int* __restrict__ cate,
    const float* __restrict__ emb,
    const float* __restrict__ hist_sum, const float* __restrict__ last_out,
    const float* __restrict__ fc1w, const float* __restrict__ fc1b,
    const float* __restrict__ pa1,
    const float* __restrict__ fc2w, const float* __restrict__ fc2b,
    const float* __restrict__ pa2,
    const float* __restrict__ fc3w, const float* __restrict__ fc3b,
    float* __restrict__ out)
{
    __shared__ float sX[320], sH1[200], sH2[80];
    int b = blockIdx.x, tid = threadIdx.x;
    int it = item[b], ct = cate[b];
    for (int i = tid; i < 320; i += 128) {
        float val;
        if (i < 64)       val = emb[(size_t)it * 64 + i];
        else if (i < 128) val = emb[(size_t)ct * 64 + (i - 64)];
        else if (i < 256) val = hist_sum[(size_t)b * 128 + (i - 128)];
        else              val = last_out[(size_t)b * 64 + (i - 256)];
        sX[i] = val;
    }
    __syncthreads();
    float a1 = pa1[0];
    for (int o = tid; o < 200; o += 128) {
        const float4* w = (const float4*)(fc1w + o * 320);
        float acc = fc1b[o];
#pragma unroll
        for (int q = 0; q < 80; ++q) {
            float4 ww = w[q];
            const float4 x4 = *(const float4*)&sX[q * 4];
            acc += ww.x * x4.x + ww.y * x4.y + ww.z * x4.z + ww.w * x4.w;
        }
        sH1[o] = acc > 0.f ? acc : a1 * acc;
    }
    __syncthreads();
    float a2 = pa2[0];
    for (int o = tid; o < 80; o += 128) {
        const float4* w = (const float4*)(fc2w + o * 200);
        float acc = fc2b[o];
#pragma unroll
        for (int q = 0; q < 50; ++q) {
            float4 ww = w[q];
            const float4 x4 = *(const float4*)&sH1[q * 4];
            acc += ww.x * x4.x + ww.y * x4.y + ww.z * x4.z + ww.w * x4.w;
        }
        sH2[o] = acc > 0.f ? acc : a2 * acc;
    }
    __syncthreads();
    if (tid < 2) {
        const float4* w = (const float4*)(fc3w + tid * 80);
        float acc = fc3b[tid];
#pragma unroll
        for (int q = 0; q < 20; ++q) {
            float4 ww = w[q];
            const float4 x4 = *(const float4*)&sH2[q * 4];
            acc += ww.x * x4.x + ww.y * x4.y + ww.z * x4.z + ww.w * x4.w;
        }
        out[b * 2 + tid] = acc;
    }
}

extern "C" void kernel_launch(void* const* d_in, const int* in_sizes, int n_in,
                              void* d_out, int out_size, void* d_ws, size_t ws_size,
                              hipStream_t stream) {
    (void)in_sizes; (void)n_in; (void)out_size; (void)ws_size;
    const int*   item      = (const int*)d_in[0];
    const int*   cate      = (const int*)d_in[1];
    const int*   hist_item = (const int*)d_in[2];
    const int*   hist_cate = (const int*)d_in[3];
    const float* mask = (const float*)d_in[4];
    const float* emb  = (const float*)d_in[5];
    const float* Wih  = (const float*)d_in[6];
    const float* Whh  = (const float*)d_in[7];
    const float* bih  = (const float*)d_in[8];
    const float* bhh  = (const float*)d_in[9];
    const float* Wp   = (const float*)d_in[10];
    const float* bp   = (const float*)d_in[11];
    const float* Wo   = (const float*)d_in[12];
    const float* bo   = (const float*)d_in[13];
    const float* M0   = (const float*)d_in[14];
    const float* fc1w = (const float*)d_in[15];
    const float* fc1b = (const float*)d_in[16];
    const float* pa1  = (const float*)d_in[17];
    const float* fc2w = (const float*)d_in[18];
    const float* fc2b = (const float*)d_in[19];
    const float* pa2  = (const float*)d_in[20];
    const float* fc3w = (const float*)d_in[21];
    const float* fc3b = (const float*)d_in[22];

    float* GIi = (float*)d_ws;                                   // V*192 f32
    float* GIc = GIi + (size_t)VV * GG;                          // V*192 f32
    float* hist_sum = GIc + (size_t)VV * GG;                     // B*128 f32
    float* last_out = hist_sum + (size_t)BB * 128;               // B*64 f32
    int* seqlen = (int*)(last_out + (size_t)BB * 64);            // B int

    build_tables<<<(VV + 63) / 64, 192, 0, stream>>>(emb, Wih, bih, GIi, GIc);
    hist_stats<<<BB, 128, 0, stream>>>(hist_item, hist_cate, mask, emb, hist_sum, seqlen);
    mimn_rnn<<<BB / RPB, 512, 0, stream>>>(hist_item, hist_cate, mask, Wih, Whh, bhh,
                                           Wp, bp, Wo, bo, M0, GIi, GIc, seqlen, last_out);
    final_mlp<<<BB, 128, 0, stream>>>(item, cate, emb, hist_sum, last_out,
                                      fc1w, fc1b, pa1, fc2w, fc2b, pa2, fc3w, fc3b,
                                      (float*)d_out);
}

// Round 3
// 4745.943 us; speedup vs baseline: 1.9266x; 1.9266x over previous
//
#include <hip/hip_runtime.h>

#define VV 100000
#define BB 2048
#define TT 200
#define GG 192   // 3*C
#define PP 514
#define RPB 8    // batch rows per block (mimn_rnn)

__device__ __forceinline__ float sigmf(float x) { return 1.0f / (1.0f + expf(-x)); }
__device__ __forceinline__ float softplusf(float x) {
    return fmaxf(x, 0.0f) + log1pf(expf(-fabsf(x)));
}
__device__ __forceinline__ float wred64(float x) {
#pragma unroll
    for (int m = 32; m >= 1; m >>= 1) x += __shfl_xor(x, m, 64);
    return x;
}

// ---------------- K0: per-vocab GI tables (bih folded into GI_item) -------------
__global__ __launch_bounds__(192) void build_tables(
    const float* __restrict__ emb,   // V x 64
    const float* __restrict__ Wih,   // 192 x 256
    const float* __restrict__ bih,   // 192
    float* __restrict__ GIi, float* __restrict__ GIc)  // V x 192 each
{
    __shared__ float sE[64 * 64];
    int tid = threadIdx.x;           // = n
    int v0 = blockIdx.x * 64;
    for (int i = tid; i < 64 * 64; i += 192) {
        int vv = i >> 6, k = i & 63;
        int gv = v0 + vv;
        sE[i] = (gv < VV) ? emb[(size_t)gv * 64 + k] : 0.0f;
    }
    __syncthreads();
    int n = tid;
    float bi = bih[n];
    {
        float4 w[16];
        const float4* wp = (const float4*)(Wih + n * 256);
#pragma unroll
        for (int q = 0; q < 16; ++q) w[q] = wp[q];
        for (int vv = 0; vv < 64; ++vv) {
            int gv = v0 + vv;
            if (gv >= VV) break;
            const float4* e = (const float4*)&sE[vv * 64];
            float acc = bi;
#pragma unroll
            for (int q = 0; q < 16; ++q) {
                float4 ee = e[q];
                acc += w[q].x * ee.x + w[q].y * ee.y + w[q].z * ee.z + w[q].w * ee.w;
            }
            GIi[(size_t)gv * GG + n] = acc;
        }
    }
    {
        float4 w[16];
        const float4* wp = (const float4*)(Wih + n * 256 + 64);
#pragma unroll
        for (int q = 0; q < 16; ++q) w[q] = wp[q];
        for (int vv = 0; vv < 64; ++vv) {
            int gv = v0 + vv;
            if (gv >= VV) break;
            const float4* e = (const float4*)&sE[vv * 64];
            float acc = 0.0f;
#pragma unroll
            for (int q = 0; q < 16; ++q) {
                float4 ee = e[q];
                acc += w[q].x * ee.x + w[q].y * ee.y + w[q].z * ee.z + w[q].w * ee.w;
            }
            GIc[(size_t)gv * GG + n] = acc;
        }
    }
}

// ---------------- K1: hist_sum + seq_len ----------------------------------------
__global__ __launch_bounds__(128) void hist_stats(
    const int* __restrict__ hist_item, const int* __restrict__ hist_cate,
    const float* __restrict__ mask, const float* __restrict__ emb,
    float* __restrict__ hist_sum, int* __restrict__ seqlen)
{
    int b = blockIdx.x, tid = threadIdx.x;
    const int* hidx = (tid < 64) ? hist_item : hist_cate;   // wave-uniform
    int j = tid & 63;
    float acc = 0.f;
    for (int t = 0; t < TT; ++t) {
        float m = mask[b * TT + t];
        int idx = hidx[b * TT + t];
        acc += m * emb[(size_t)idx * 64 + j];
    }
    hist_sum[(size_t)b * 128 + tid] = acc;
    if (tid < 64) {
        float s = 0.f;
        for (int t = tid; t < TT; t += 64) s += mask[b * TT + t];
        s = wred64(s);
        if (tid == 0) seqlen[b] = (int)(s + 0.5f);
    }
}

// ---------------- K2: recurrence, weight-stationary, 1024 thr, 8 rows -----------
// Thread roles (wave-aligned):
//   [0,384):    gi = read@Wih_r^T, (n = tid%192, k-half = tid/192), 16 f4 weights
//   [384,768):  gh = h@Whh^T,      (n = u%192,  k-half32 = u/192),   8 f4 weights
//   [768,1024): gather prefetch (next step's GIi/GIc, held in W[s].x/.y)
//   all:        one Wp row-slice (n,khalf32) in Wq[8] for phase 3
__global__ __launch_bounds__(1024) void mimn_rnn(
    const int* __restrict__ hist_item, const int* __restrict__ hist_cate,
    const float* __restrict__ mask,
    const float* __restrict__ Wih,   // 192x256 (cols 128..255 = read part)
    const float* __restrict__ Whh,   // 192x64
    const float* __restrict__ bhh,   // 192
    const float* __restrict__ Wp,    // 514x64
    const float* __restrict__ bp,    // 514
    const float* __restrict__ Wo,    // 64x192
    const float* __restrict__ bo,    // 64
    const float* __restrict__ M0,    // 4x128
    const float* __restrict__ GIi, const float* __restrict__ GIc,
    const int* __restrict__ seqlen,
    float* __restrict__ last_out)    // B x 64
{
    __shared__ float sU[8224];        // ph1: 5x1536 partials; ph3/4: 2x(8x514) p
    __shared__ float sM [RPB * 512];
    __shared__ float sRd[RPB * 128];
    __shared__ float sH [RPB * 64];
    __shared__ float sHn[RPB * 64];
    __shared__ float sBp[PP];
    __shared__ float sMask[RPB * TT];
    __shared__ int   sHI[RPB * TT];
    __shared__ int   sHC[RPB * TT];

    const int tid = threadIdx.x;
    const int b0 = blockIdx.x * RPB;

    // ---- init staged state ----
    for (int i = tid; i < RPB * 64; i += 1024) { sH[i] = 0.f; sHn[i] = 0.f; }
    for (int i = tid; i < RPB * 128; i += 1024) sRd[i] = 0.f;
    for (int i = tid; i < RPB * 512; i += 1024) sM[i] = M0[i & 511];
    for (int i = tid; i < PP; i += 1024) sBp[i] = bp[i];
    for (int i = tid; i < RPB * TT; i += 1024) {
        int r = i / TT, tt = i - r * TT;
        sMask[i] = mask[(size_t)(b0 + r) * TT + tt];
        sHI[i]   = hist_item[(size_t)(b0 + r) * TT + tt];
        sHC[i]   = hist_cate[(size_t)(b0 + r) * TT + tt];
    }

    // ---- hoist weights to registers ----
    float4 W[16];
    float4 Wq[8];
    float bhh_r = 0.f;
    int nA = 0, khA = 0;
    if (tid < 384) {
        nA = tid % 192; khA = tid / 192;
        const float4* ws = (const float4*)(Wih + nA * 256 + 128 + khA * 64);
#pragma unroll
        for (int q = 0; q < 16; ++q) W[q] = ws[q];
    } else if (tid < 768) {
        int u = tid - 384;
        nA = u % 192; khA = u / 192;
        const float4* ws = (const float4*)(Whh + nA * 64 + khA * 32);
#pragma unroll
        for (int q = 0; q < 8; ++q) W[q] = ws[q];
        bhh_r = (khA == 0) ? bhh[nA] : 0.f;
    }
    const int npP = (tid < 514) ? tid : tid - 514;
    const int khP = (tid < 514) ? 0 : 1;
    {
        const float4* ws = (const float4*)(Wp + npP * 64 + khP * 32);
#pragma unroll
        for (int q = 0; q < 8; ++q) Wq[q] = ws[q];
    }
    int ts = 0;
    if (tid < 512) {
        int q = seqlen[b0 + (tid >> 6)] - 1;
        ts = q < 0 ? 0 : (q > TT - 1 ? TT - 1 : q);
    }
    __syncthreads();

    // ---- initial gather prefetch (t = 0) ----
    if (tid >= 768) {
        int g = tid - 768;
#pragma unroll
        for (int s = 0; s < 6; ++s) {
            int idx = g + 256 * s; int r = idx / 192, n = idx - r * 192;
            W[s].x = GIi[(size_t)sHI[r * TT] * GG + n];
            W[s].y = GIc[(size_t)sHC[r * TT] * GG + n];
        }
    }

    for (int t = 0; t < TT; ++t) {
        // ---- phase 1: gi/gh partials + gather commit & next-step prefetch ----
        if (tid < 384) {
            float acc[RPB];
#pragma unroll
            for (int r = 0; r < RPB; ++r) acc[r] = 0.f;
            const int kb = khA * 64;
#pragma unroll
            for (int q = 0; q < 16; ++q) {
                float4 w = W[q];
#pragma unroll
                for (int r = 0; r < RPB; ++r) {
                    float4 a = *(const float4*)&sRd[r * 128 + kb + q * 4];
                    acc[r] += w.x * a.x + w.y * a.y + w.z * a.z + w.w * a.w;
                }
            }
            float* dst = &sU[khA * 1536];
#pragma unroll
            for (int r = 0; r < RPB; ++r) dst[r * GG + nA] = acc[r];
        } else if (tid < 768) {
            float acc[RPB];
#pragma unroll
            for (int r = 0; r < RPB; ++r) acc[r] = bhh_r;
            const int kb = khA * 32;
#pragma unroll
            for (int q = 0; q < 8; ++q) {
                float4 w = W[q];
#pragma unroll
                for (int r = 0; r < RPB; ++r) {
                    float4 a = *(const float4*)&sH[r * 64 + kb + q * 4];
                    acc[r] += w.x * a.x + w.y * a.y + w.z * a.z + w.w * a.w;
                }
            }
            float* dst = &sU[(2 + khA) * 1536];
#pragma unroll
            for (int r = 0; r < RPB; ++r) dst[r * GG + nA] = acc[r];
        } else {
            int g = tid - 768;
#pragma unroll
            for (int s = 0; s < 6; ++s) {
                int idx = g + 256 * s;
                sU[6144 + idx] = W[s].x + W[s].y;
            }
            int tn = (t + 1 < TT) ? t + 1 : TT - 1;
#pragma unroll
            for (int s = 0; s < 6; ++s) {
                int idx = g + 256 * s; int r = idx / 192, n = idx - r * 192;
                W[s].x = GIi[(size_t)sHI[r * TT + tn] * GG + n];
                W[s].y = GIc[(size_t)sHC[r * TT + tn] * GG + n];
            }
        }
        __syncthreads();
        // ---- phase 2: GRU gates; commit h ----
        if (tid < 512) {
            int r = tid >> 6, lane = tid & 63;
            int base = r * GG + lane;
            float i_r = sU[base]        + sU[1536 + base]        + sU[6144 + base];
            float h_r = sU[3072 + base] + sU[4608 + base];
            float i_z = sU[64 + base]   + sU[1536 + 64 + base]   + sU[6144 + 64 + base];
            float h_z = sU[3072 + 64 + base]  + sU[4608 + 64 + base];
            float i_n = sU[128 + base]  + sU[1536 + 128 + base]  + sU[6144 + 128 + base];
            float h_n = sU[3072 + 128 + base] + sU[4608 + 128 + base];
            float rg = sigmf(i_r + h_r);
            float zg = sigmf(i_z + h_z);
            float ng = tanhf(i_n + rg * h_n);
            float h_old = sH[r * 64 + lane];
            float hn = (1.f - zg) * ng + zg * h_old;
            float mt = sMask[r * TT + t];
            sHn[r * 64 + lane] = hn;
            sH[r * 64 + lane] = (mt > 0.f) ? hn : h_old;
        }
        __syncthreads();
        // ---- phase 3: p partials = h_new @ Wp^T (per-thread (n, k-half32)) ----
        {
            float acc[RPB];
#pragma unroll
            for (int r = 0; r < RPB; ++r) acc[r] = 0.f;
            const int kb = khP * 32;
#pragma unroll
            for (int q = 0; q < 8; ++q) {
                float4 w = Wq[q];
#pragma unroll
                for (int r = 0; r < RPB; ++r) {
                    float4 a = *(const float4*)&sHn[r * 64 + kb + q * 4];
                    acc[r] += w.x * a.x + w.y * a.y + w.z * a.z + w.w * a.w;
                }
            }
            float* dst = &sU[khP * 4112];
#pragma unroll
            for (int r = 0; r < RPB; ++r) dst[r * PP + npP] = acc[r];
        }
        if (tid >= 1020) {                       // 4 leftover (kh1, n=510..513) slots
            int np2 = 510 + (tid - 1020);
            const float4* ws = (const float4*)(Wp + np2 * 64 + 32);
            float acc[RPB];
#pragma unroll
            for (int r = 0; r < RPB; ++r) acc[r] = 0.f;
#pragma unroll
            for (int q = 0; q < 8; ++q) {
                float4 w = ws[q];
#pragma unroll
                for (int r = 0; r < RPB; ++r) {
                    float4 a = *(const float4*)&sHn[r * 64 + 32 + q * 4];
                    acc[r] += w.x * a.x + w.y * a.y + w.z * a.z + w.w * a.w;
                }
            }
#pragma unroll
            for (int r = 0; r < RPB; ++r) sU[4112 + r * PP + np2] = acc[r];
        }
        __syncthreads();
        // ---- phase 4: NTM addressing, one wave per row ----
        if (tid < 512) {
            int row = tid >> 6, lane = tid & 63;
            const int pb = row * PP;
#define PV(n) (sU[pb + (n)] + sU[4112 + pb + (n)] + sBp[(n)])
            float kr1 = tanhf(PV(lane)),       kr2 = tanhf(PV(64 + lane));
            float beta_r = softplusf(PV(128));
            float kw1 = tanhf(PV(129 + lane)), kw2 = tanhf(PV(193 + lane));
            float beta_w = softplusf(PV(257));
            float er1 = sigmf(PV(258 + lane)), er2 = sigmf(PV(322 + lane));
            float ad1 = tanhf(PV(386 + lane)), ad2 = tanhf(PV(450 + lane));
#undef PV
            float M1[4], M2[4];
#pragma unroll
            for (int s = 0; s < 4; ++s) {
                M1[s] = sM[row * 512 + s * 128 + lane];
                M2[s] = sM[row * 512 + s * 128 + 64 + lane];
            }
            float nkr = sqrtf(wred64(kr1 * kr1 + kr2 * kr2)) + 1e-8f;
            float nkw = sqrtf(wred64(kw1 * kw1 + kw2 * kw2)) + 1e-8f;
            float Kr[4], Kw[4];
#pragma unroll
            for (int s = 0; s < 4; ++s) {
                float nM = sqrtf(wred64(M1[s] * M1[s] + M2[s] * M2[s])) + 1e-8f;
                float dr = wred64(kr1 * M1[s] + kr2 * M2[s]);
                float dw = wred64(kw1 * M1[s] + kw2 * M2[s]);
                Kr[s] = dr / (nkr * nM);
                Kw[s] = dw / (nkw * nM);
            }
            float wr_[4], ww_[4];
            {
                float mx = fmaxf(fmaxf(beta_r * Kr[0], beta_r * Kr[1]),
                                 fmaxf(beta_r * Kr[2], beta_r * Kr[3]));
                float sum = 0.f;
#pragma unroll
                for (int s = 0; s < 4; ++s) { wr_[s] = expf(beta_r * Kr[s] - mx); sum += wr_[s]; }
                float inv = 1.f / sum;
#pragma unroll
                for (int s = 0; s < 4; ++s) wr_[s] *= inv;
            }
            {
                float mx = fmaxf(fmaxf(beta_w * Kw[0], beta_w * Kw[1]),
                                 fmaxf(beta_w * Kw[2], beta_w * Kw[3]));
                float sum = 0.f;
#pragma unroll
                for (int s = 0; s < 4; ++s) { ww_[s] = expf(beta_w * Kw[s] - mx); sum += ww_[s]; }
                float inv = 1.f / sum;
#pragma unroll
                for (int s = 0; s < 4; ++s) ww_[s] *= inv;
            }
            float rn1 = 0.f, rn2 = 0.f;
#pragma unroll
            for (int s = 0; s < 4; ++s) { rn1 += wr_[s] * M1[s]; rn2 += wr_[s] * M2[s]; }
            float mt = sMask[row * TT + t];
            bool vld = mt > 0.f;
            if (vld) {
#pragma unroll
                for (int s = 0; s < 4; ++s) {
                    sM[row * 512 + s * 128 + lane]      = M1[s] * (1.f - ww_[s] * er1) + ww_[s] * ad1;
                    sM[row * 512 + s * 128 + 64 + lane] = M2[s] * (1.f - ww_[s] * er2) + ww_[s] * ad2;
                }
                sRd[row * 128 + lane]      = rn1;
                sRd[row * 128 + 64 + lane] = rn2;
            }
            if (t == ts) {
                sU[pb + lane] = rn1; sU[pb + 64 + lane] = rn2;
                __asm__ volatile("s_waitcnt lgkmcnt(0)" ::: "memory");
                float acc = bo[lane];
                const float* wo = Wo + lane * GG;
                for (int k = 0; k < 64; ++k)  acc += sHn[row * 64 + k] * wo[k];
                for (int k = 0; k < 128; ++k) acc += sU[pb + k] * wo[64 + k];
                if (!vld) acc = 0.f;
                last_out[(size_t)(b0 + row) * 64 + lane] = acc;
            }
        }
        __syncthreads();
    }
}

// ---------------- K3: final MLP head --------------------------------------------
__global__ __launch_bounds__(128) void final_mlp(
    const int* __restrict__ item, const int* __restrict__ cate,
    const float* __restrict__ emb,
    const float* __restrict__ hist_sum, const float* __restrict__ last_out,
    const float* __restrict__ fc1w, const float* __restrict__ fc1b,
    const float* __restrict__ pa1,
    const float* __restrict__ fc2w, const float* __restrict__ fc2b,
    const float* __restrict__ pa2,
    const float* __restrict__ fc3w, const float* __restrict__ fc3b,
    float* __restrict__ out)
{
    __shared__ float sX[320], sH1[200], sH2[80];
    int b = blockIdx.x, tid = threadIdx.x;
    int it = item[b], ct = cate[b];
    for (int i = tid; i < 320; i += 128) {
        float val;
        if (i < 64)       val = emb[(size_t)it * 64 + i];
        else if (i < 128) val = emb[(size_t)ct * 64 + (i - 64)];
        else if (i < 256) val = hist_sum[(size_t)b * 128 + (i - 128)];
        else              val = last_out[(size_t)b * 64 + (i - 256)];
        sX[i] = val;
    }
    __syncthreads();
    float a1 = pa1[0];
    for (int o = tid; o < 200; o += 128) {
        const float4* w = (const float4*)(fc1w + o * 320);
        float acc = fc1b[o];
#pragma unroll
        for (int q = 0; q < 80; ++q) {
            float4 ww = w[q];
            const float4 x4 = *(const float4*)&sX[q * 4];
            acc += ww.x * x4.x + ww.y * x4.y + ww.z * x4.z + ww.w * x4.w;
        }
        sH1[o] = acc > 0.f ? acc : a1 * acc;
    }
    __syncthreads();
    float a2 = pa2[0];
    for (int o = tid; o < 80; o += 128) {
        const float4* w = (const float4*)(fc2w + o * 200);
        float acc = fc2b[o];
#pragma unroll
        for (int q = 0; q < 50; ++q) {
            float4 ww = w[q];
            const float4 x4 = *(const float4*)&sH1[q * 4];
            acc += ww.x * x4.x + ww.y * x4.y + ww.z * x4.z + ww.w * x4.w;
        }
        sH2[o] = acc > 0.f ? acc : a2 * acc;
    }
    __syncthreads();
    if (tid < 2) {
        const float4* w = (const float4*)(fc3w + tid * 80);
        float acc = fc3b[tid];
#pragma unroll
        for (int q = 0; q < 20; ++q) {
            float4 ww = w[q];
            const float4 x4 = *(const float4*)&sH2[q * 4];
            acc += ww.x * x4.x + ww.y * x4.y + ww.z * x4.z + ww.w * x4.w;
        }
        out[b * 2 + tid] = acc;
    }
}

extern "C" void kernel_launch(void* const* d_in, const int* in_sizes, int n_in,
                              void* d_out, int out_size, void* d_ws, size_t ws_size,
                              hipStream_t stream) {
    (void)in_sizes; (void)n_in; (void)out_size; (void)ws_size;
    const int*   item      = (const int*)d_in[0];
    const int*   cate      = (const int*)d_in[1];
    const int*   hist_item = (const int*)d_in[2];
    const int*   hist_cate = (const int*)d_in[3];
    const float* mask = (const float*)d_in[4];
    const float* emb  = (const float*)d_in[5];
    const float* Wih  = (const float*)d_in[6];
    const float* Whh  = (const float*)d_in[7];
    const float* bih  = (const float*)d_in[8];
    const float* bhh  = (const float*)d_in[9];
    const float* Wp   = (const float*)d_in[10];
    const float* bp   = (const float*)d_in[11];
    const float* Wo   = (const float*)d_in[12];
    const float* bo   = (const float*)d_in[13];
    const float* M0   = (const float*)d_in[14];
    const float* fc1w = (const float*)d_in[15];
    const float* fc1b = (const float*)d_in[16];
    const float* pa1  = (const float*)d_in[17];
    const float* fc2w = (const float*)d_in[18];
    const float* fc2b = (const float*)d_in[19];
    const float* pa2  = (const float*)d_in[20];
    const float* fc3w = (const float*)d_in[21];
    const float* fc3b = (const float*)d_in[22];

    float* GIi = (float*)d_ws;                                   // V*192 f32
    float* GIc = GIi + (size_t)VV * GG;                          // V*192 f32
    float* hist_sum = GIc + (size_t)VV * GG;                     // B*128 f32
    float* last_out = hist_sum + (size_t)BB * 128;               // B*64 f32
    int* seqlen = (int*)(last_out + (size_t)BB * 64);            // B int

    build_tables<<<(VV + 63) / 64, 192, 0, stream>>>(emb, Wih, bih, GIi, GIc);
    hist_stats<<<BB, 128, 0, stream>>>(hist_item, hist_cate, mask, emb, hist_sum, seqlen);
    mimn_rnn<<<BB / RPB, 1024, 0, stream>>>(hist_item, hist_cate, mask, Wih, Whh, bhh,
                                            Wp, bp, Wo, bo, M0, GIi, GIc, seqlen, last_out);
    final_mlp<<<BB, 128, 0, stream>>>(item, cate, emb, hist_sum, last_out,
                                      fc1w, fc1b, pa1, fc2w, fc2b, pa2, fc3w, fc3b,
                                      (float*)d_out);
}